// Round 1
// baseline (550.365 us; speedup 1.0000x reference)
//
#include <hip/hip_runtime.h>

constexpr int D_IN  = 64;
constexpr int D_H1  = 32;
constexpr int D_H2  = 64;
constexpr int D_OUT = 128;
constexpr int NSEG  = 8192;

constexpr int BLOCK = 256;       // 4 waves
constexpr int RT    = 64;        // rows per tile
constexpr int TPB   = 8;         // tiles per block -> 1954 blocks

typedef __bf16 bfx8 __attribute__((ext_vector_type(8)));
typedef __bf16 bfx4 __attribute__((ext_vector_type(4)));
typedef float  fx4  __attribute__((ext_vector_type(4)));

// MFMA 16x16x32 bf16 layouts (m89-verified):
//   A: m = lane&15, k = (lane>>4)*8 + j   (8 contiguous k -> ds_read_b128)
//   B: n = lane&15, k = (lane>>4)*8 + i
//   D: row(m) = (lane>>4)*4 + reg, col(n) = lane&15

__global__ __launch_bounds__(BLOCK, 3) void mlp_seg_mfma(
    const float* __restrict__ f, const int* __restrict__ seg,
    const float* __restrict__ W1, const float* __restrict__ b1,
    const float* __restrict__ W2, const float* __restrict__ b2,
    const float* __restrict__ W3, const float* __restrict__ b3,
    float* __restrict__ sums, float* __restrict__ counts,
    int N, int ntiles)
{
    __shared__ __align__(16) __bf16 sf [RT * 64];    // 8 KB  (XOR-swizzled chunks)
    __shared__ __align__(16) __bf16 sh1[RT * 32];    // 4 KB
    __shared__ __align__(16) __bf16 sh2[RT * 64];    // 8 KB
    __shared__ __align__(16) __bf16 syT[D_OUT * 64]; // 16 KB transposed [col][row], XOR-swizzled
    __shared__ int sseg[RT];

    const int tid  = threadIdx.x;
    const int wv   = tid >> 6;
    const int lane = tid & 63;
    const int lr   = lane & 15;
    const int quad = lane >> 4;
    const int m0   = wv * 16;          // this wave's 16-row slice of the tile
    const int ar   = m0 + lr;          // A-fragment row for this lane

    // ---- weight B-fragments + biases -> registers (one-time, L2-cached) ----
    bfx8 fw1[2][2];                    // [ntile][kstep]  W1[64][32]
    #pragma unroll
    for (int j = 0; j < 2; ++j)
        #pragma unroll
        for (int ks = 0; ks < 2; ++ks)
            #pragma unroll
            for (int i = 0; i < 8; ++i)
                fw1[j][ks][i] = (__bf16)W1[(ks*32 + quad*8 + i)*D_H1 + j*16 + lr];

    bfx8 fw2[4];                       // W2[32][64], K=32 single step
    #pragma unroll
    for (int j = 0; j < 4; ++j)
        #pragma unroll
        for (int i = 0; i < 8; ++i)
            fw2[j][i] = (__bf16)W2[(quad*8 + i)*D_H2 + j*16 + lr];

    bfx8 fw3[8][2];                    // W3[64][128]
    #pragma unroll
    for (int j = 0; j < 8; ++j)
        #pragma unroll
        for (int ks = 0; ks < 2; ++ks)
            #pragma unroll
            for (int i = 0; i < 8; ++i)
                fw3[j][ks][i] = (__bf16)W3[(ks*32 + quad*8 + i)*D_OUT + j*16 + lr];

    float rb1[2], rb2[4], rb3[8];
    #pragma unroll
    for (int j = 0; j < 2; ++j) rb1[j] = b1[j*16 + lr];
    #pragma unroll
    for (int j = 0; j < 4; ++j) rb2[j] = b2[j*16 + lr];
    #pragma unroll
    for (int j = 0; j < 8; ++j) rb3[j] = b3[j*16 + lr];

    // ---- persistent segment-run state (two 128-thread groups) ----
    const int colA = tid & 127;        // owned output column
    const int grp  = tid >> 7;         // group 0: rows 0..31, group 1: rows 32..63
    int   cur_seg = -1;
    float run_sum = 0.f;
    int   run_len = 0;

    const int t0 = blockIdx.x * TPB;
    const int t1 = min(t0 + TPB, ntiles);

    for (int t = t0; t < t1; ++t) {
        const int R0 = t * RT;

        // ---- stage f tile: global float4 (coalesced) -> bf16 -> swizzled LDS ----
        const float4* f4 = (const float4*)f + (size_t)R0 * 16;
        #pragma unroll
        for (int i = 0; i < 4; ++i) {
            const int idx4 = tid + i * 256;
            float4 q = make_float4(0.f, 0.f, 0.f, 0.f);
            if ((size_t)R0 * 64 + (size_t)idx4 * 4 < (size_t)N * 64) q = f4[idx4];
            const int r = idx4 >> 4;
            const int c = (idx4 & 15) * 4;
            bfx4 v;
            v[0] = (__bf16)q.x; v[1] = (__bf16)q.y;
            v[2] = (__bf16)q.z; v[3] = (__bf16)q.w;
            const int pe = r*64 + ((((c >> 3) ^ (r & 7))) << 3) + (c & 7);
            *(bfx4*)&sf[pe] = v;
        }
        if (tid < RT) sseg[tid] = (R0 + tid < N) ? seg[R0 + tid] : -2;
        __syncthreads();

        // ---- L1: [16,64]@[64,32] per wave ----
        fx4 acc1[2] = {{0,0,0,0},{0,0,0,0}};
        #pragma unroll
        for (int ks = 0; ks < 2; ++ks) {
            bfx8 a = *(const bfx8*)&sf[ar*64 + (((ks*4 + quad) ^ (ar & 7)) << 3)];
            #pragma unroll
            for (int j = 0; j < 2; ++j)
                acc1[j] = __builtin_amdgcn_mfma_f32_16x16x32_bf16(a, fw1[j][ks], acc1[j], 0, 0, 0);
        }
        #pragma unroll
        for (int j = 0; j < 2; ++j)
            #pragma unroll
            for (int rg = 0; rg < 4; ++rg) {
                const int row = m0 + quad*4 + rg;
                const int col = j*16 + lr;
                const float v = fmaxf(acc1[j][rg] + rb1[j], 0.f);
                sh1[row*32 + (((col >> 3) ^ (row & 3)) << 3) + (col & 7)] = (__bf16)v;
            }
        // no barrier: sh1 rows [m0, m0+16) are written and read by this wave only

        // ---- L2: [16,32]@[32,64], K=32 single step ----
        fx4 acc2[4] = {{0,0,0,0},{0,0,0,0},{0,0,0,0},{0,0,0,0}};
        {
            bfx8 a = *(const bfx8*)&sh1[ar*32 + ((quad ^ (ar & 3)) << 3)];
            #pragma unroll
            for (int j = 0; j < 4; ++j)
                acc2[j] = __builtin_amdgcn_mfma_f32_16x16x32_bf16(a, fw2[j], acc2[j], 0, 0, 0);
        }
        #pragma unroll
        for (int j = 0; j < 4; ++j)
            #pragma unroll
            for (int rg = 0; rg < 4; ++rg) {
                const int row = m0 + quad*4 + rg;
                const int col = j*16 + lr;
                const float v = fmaxf(acc2[j][rg] + rb2[j], 0.f);
                sh2[row*64 + (((col >> 3) ^ (row & 7)) << 3) + (col & 7)] = (__bf16)v;
            }

        // ---- L3: [16,64]@[64,128], two halves of 4 n-tiles (caps VGPR peak) ----
        // Output goes to syT TRANSPOSED [col][row] so the scan below can
        // ds_read_b128 8 rows per lane. A lane's 4 rg-values are 4 contiguous
        // rows at one col -> single ds_write_b64 each.
        #pragma unroll
        for (int h = 0; h < 2; ++h) {
            fx4 acc3[4] = {{0,0,0,0},{0,0,0,0},{0,0,0,0},{0,0,0,0}};
            #pragma unroll
            for (int ks = 0; ks < 2; ++ks) {
                bfx8 a = *(const bfx8*)&sh2[ar*64 + (((ks*4 + quad) ^ (ar & 7)) << 3)];
                #pragma unroll
                for (int j = 0; j < 4; ++j)
                    acc3[j] = __builtin_amdgcn_mfma_f32_16x16x32_bf16(a, fw3[h*4 + j][ks], acc3[j], 0, 0, 0);
            }
            #pragma unroll
            for (int j = 0; j < 4; ++j) {
                bfx4 w;
                #pragma unroll
                for (int rg = 0; rg < 4; ++rg)
                    w[rg] = (__bf16)(acc3[j][rg] + rb3[h*4 + j]);
                const int col  = (h*4 + j)*16 + lr;
                const int row0 = m0 + quad*4;          // 4 contiguous rows, 8-aligned group
                // element = col*64 + ((row0>>3)^(col&7))*8 + (row0&7); row0&7 = (quad&1)*4
                *(bfx4*)&syT[col*64 + (((row0 >> 3) ^ (col & 7)) << 3) + (quad & 1)*4] = w;
            }
        }
        __syncthreads();   // syT written by all waves, read by all below

        // ---- segment-run accumulation: 4 chunks of 8 rows, vectorized ----
        // seg_ids sorted => s[first]==s[last] implies whole chunk same segment.
        #pragma unroll
        for (int ch = 0; ch < 4; ++ch) {
            const int r8 = grp*32 + ch*8;
            const bfx8 v8 = *(const bfx8*)&syT[colA*64 + (((grp*4 + ch) ^ (colA & 7)) << 3)];
            const int sA = sseg[r8];
            const int sB = sseg[r8 + 7];
            if (sA == sB) {                            // fast path (~93% of chunks)
                float sum = 0.f;
                #pragma unroll
                for (int k = 0; k < 8; ++k) sum += (float)v8[k];
                if (sA != cur_seg) {                   // uniform within group
                    if (cur_seg >= 0) {
                        atomicAdd(&sums[(size_t)cur_seg * D_OUT + colA], run_sum);
                        if (colA == 0) atomicAdd(&counts[cur_seg], (float)run_len);
                    }
                    cur_seg = sA; run_sum = sum; run_len = 8;
                } else {
                    run_sum += sum; run_len += 8;
                }
            } else {                                   // boundary chunk: per-row, from regs
                #pragma unroll
                for (int k = 0; k < 8; ++k) {
                    const int s = sseg[r8 + k];
                    if (s != cur_seg) {
                        if (cur_seg >= 0) {
                            atomicAdd(&sums[(size_t)cur_seg * D_OUT + colA], run_sum);
                            if (colA == 0) atomicAdd(&counts[cur_seg], (float)run_len);
                        }
                        cur_seg = s; run_sum = 0.f; run_len = 0;
                    }
                    run_sum += (float)v8[k]; run_len++;
                }
            }
        }
        __syncthreads();   // protect syT/sf overwrite next tile
    }

    if (cur_seg >= 0) {
        atomicAdd(&sums[(size_t)cur_seg * D_OUT + colA], run_sum);
        if (colA == 0) atomicAdd(&counts[cur_seg], (float)run_len);
    }
}

__global__ __launch_bounds__(256) void div_kernel(
    const float* __restrict__ sums, const float* __restrict__ counts,
    float* __restrict__ out, int total)
{
    const int i = blockIdx.x * 256 + threadIdx.x;
    if (i < total) out[i] = sums[i] / fmaxf(counts[i >> 7], 1.f);
}

extern "C" void kernel_launch(void* const* d_in, const int* in_sizes, int n_in,
                              void* d_out, int out_size, void* d_ws, size_t ws_size,
                              hipStream_t stream) {
    const float* f   = (const float*)d_in[0];
    const int*   seg = (const int*)  d_in[1];
    const float* W1 = (const float*)d_in[3];
    const float* b1 = (const float*)d_in[4];
    const float* W2 = (const float*)d_in[5];
    const float* b2 = (const float*)d_in[6];
    const float* W3 = (const float*)d_in[7];
    const float* b3 = (const float*)d_in[8];
    float* out = (float*)d_out;

    const int N = in_sizes[0] / D_IN;

    float* sums   = (float*)d_ws;                 // [NSEG * D_OUT]
    float* counts = sums + (size_t)NSEG * D_OUT;  // [NSEG]

    hipMemsetAsync(d_ws, 0, ((size_t)NSEG * D_OUT + NSEG) * sizeof(float), stream);

    const int ntiles  = (N + RT - 1) / RT;
    const int nblocks = (ntiles + TPB - 1) / TPB;
    mlp_seg_mfma<<<nblocks, BLOCK, 0, stream>>>(f, seg, W1, b1, W2, b2, W3, b3,
                                                sums, counts, N, ntiles);

    const int total = NSEG * D_OUT;
    div_kernel<<<(total + 255) / 256, 256, 0, stream>>>(sums, counts, out, total);
}

// Round 2
// 401.564 us; speedup vs baseline: 1.3706x; 1.3706x over previous
//
#include <hip/hip_runtime.h>

constexpr int D_IN  = 64;
constexpr int D_H1  = 32;
constexpr int D_H2  = 64;
constexpr int D_OUT = 128;
constexpr int NSEG  = 8192;

constexpr int BLOCK = 256;       // 4 waves
constexpr int RT    = 64;        // rows per tile
constexpr int TPB   = 8;         // tiles per block -> 1954 blocks

typedef __bf16 bfx8 __attribute__((ext_vector_type(8)));
typedef __bf16 bfx4 __attribute__((ext_vector_type(4)));
typedef float  fx4  __attribute__((ext_vector_type(4)));

// MFMA 16x16x32 bf16 layouts (m89-verified):
//   A: m = lane&15, k = (lane>>4)*8 + j   (8 contiguous k -> ds_read_b128)
//   B: n = lane&15, k = (lane>>4)*8 + i
//   D: row(m) = (lane>>4)*4 + reg, col(n) = lane&15

// Raw barrier with LDS-only ordering: avoids __syncthreads' vmcnt(0) drain
// so prefetch global loads stay in flight across the barrier.
#define BAR_LGKM() do {                                        \
    asm volatile("s_waitcnt lgkmcnt(0)" ::: "memory");         \
    __builtin_amdgcn_s_barrier();                              \
    __builtin_amdgcn_sched_barrier(0);                         \
} while (0)

__global__ __launch_bounds__(BLOCK, 3) void mlp_seg_mfma(
    const float* __restrict__ f, const int* __restrict__ seg,
    const float* __restrict__ W1, const float* __restrict__ b1,
    const float* __restrict__ W2, const float* __restrict__ b2,
    const float* __restrict__ W3, const float* __restrict__ b3,
    float* __restrict__ sums, float* __restrict__ counts,
    int N, int ntiles)
{
    __shared__ __align__(16) __bf16 sf [2][RT * 64]; // 16 KB double-buffered f tile
    __shared__ __align__(16) __bf16 sh1[RT * 32];    // 4 KB
    __shared__ __align__(16) __bf16 sh2[RT * 64];    // 8 KB
    __shared__ __align__(16) __bf16 syT[D_OUT * 64]; // 16 KB transposed [col][row], XOR-swizzled
    __shared__ int sseg[2][RT];

    const int tid  = threadIdx.x;
    const int wv   = tid >> 6;
    const int lane = tid & 63;
    const int lr   = lane & 15;
    const int quad = lane >> 4;
    const int m0   = wv * 16;          // this wave's 16-row slice for L1/L2
    const int ar   = m0 + lr;          // A-fragment row for this lane (L1/L2)

    // ---- weight B-fragments + biases -> registers (one-time, L2-cached) ----
    // L3 weights are per-wave COLUMN slices (wave wv owns cols [wv*32, wv*32+32)):
    // fw3 is 16 VGPRs instead of 64 -> total demand fits the 168-reg budget,
    // no spill / per-tile rematerialization.
    bfx8 fw1[2][2];                    // [ntile][kstep]  W1[64][32]
    #pragma unroll
    for (int j = 0; j < 2; ++j)
        #pragma unroll
        for (int ks = 0; ks < 2; ++ks)
            #pragma unroll
            for (int i = 0; i < 8; ++i)
                fw1[j][ks][i] = (__bf16)W1[(ks*32 + quad*8 + i)*D_H1 + j*16 + lr];

    bfx8 fw2[4];                       // W2[32][64], K=32 single step
    #pragma unroll
    for (int j = 0; j < 4; ++j)
        #pragma unroll
        for (int i = 0; i < 8; ++i)
            fw2[j][i] = (__bf16)W2[(quad*8 + i)*D_H2 + j*16 + lr];

    bfx8 fw3[2][2];                    // W3[64][128], cols wv*32 + j*16 + lr
    #pragma unroll
    for (int j = 0; j < 2; ++j)
        #pragma unroll
        for (int ks = 0; ks < 2; ++ks)
            #pragma unroll
            for (int i = 0; i < 8; ++i)
                fw3[j][ks][i] = (__bf16)W3[(ks*32 + quad*8 + i)*D_OUT + wv*32 + j*16 + lr];

    float rb1[2], rb2[4], rb3[2];
    #pragma unroll
    for (int j = 0; j < 2; ++j) rb1[j] = b1[j*16 + lr];
    #pragma unroll
    for (int j = 0; j < 4; ++j) rb2[j] = b2[j*16 + lr];
    #pragma unroll
    for (int j = 0; j < 2; ++j) rb3[j] = b3[wv*32 + j*16 + lr];

    // ---- persistent segment-run state (two 128-thread groups) ----
    const int colA = tid & 127;        // owned output column
    const int grp  = tid >> 7;         // group 0: rows 0..31, group 1: rows 32..63
    int   cur_seg = -1;
    float run_sum = 0.f;
    int   run_len = 0;

    const int t0 = blockIdx.x * TPB;
    const int t1 = min(t0 + TPB, ntiles);

    // ---- prologue: stage tile t0 into buffer 0 ----
    {
        const int R0 = t0 * RT;
        const float4* f4 = (const float4*)f + (size_t)R0 * 16;
        #pragma unroll
        for (int i = 0; i < 4; ++i) {
            const int idx4 = tid + i * 256;
            float4 qq = make_float4(0.f, 0.f, 0.f, 0.f);
            if ((size_t)R0 * 64 + (size_t)idx4 * 4 < (size_t)N * 64) qq = f4[idx4];
            const int r = idx4 >> 4;
            const int c = (idx4 & 15) * 4;
            bfx4 v;
            v[0] = (__bf16)qq.x; v[1] = (__bf16)qq.y;
            v[2] = (__bf16)qq.z; v[3] = (__bf16)qq.w;
            *(bfx4*)&sf[0][r*64 + (((c >> 3) ^ (r & 7)) << 3) + (c & 7)] = v;
        }
        if (tid < RT) sseg[0][tid] = (R0 + tid < N) ? seg[R0 + tid] : -2;
    }
    __syncthreads();

    int p = 0;
    for (int t = t0; t < t1; ++t, p ^= 1) {
        const int R0 = t * RT;
        const bool havenext = (t + 1 < t1);

        // ---- issue next tile's global loads EARLY (latency hides under MLP) ----
        float4 q[4];
        int rseg = -2;
        if (havenext) {
            const float4* f4n = (const float4*)f + (size_t)(R0 + RT) * 16;
            #pragma unroll
            for (int i = 0; i < 4; ++i) {
                const int idx4 = tid + i * 256;
                q[i] = make_float4(0.f, 0.f, 0.f, 0.f);
                if ((size_t)(R0 + RT) * 64 + (size_t)idx4 * 4 < (size_t)N * 64)
                    q[i] = f4n[idx4];
            }
            if (tid < RT) rseg = (R0 + RT + tid < N) ? seg[R0 + RT + tid] : -2;
        }

        // ---- L1: [16,64]@[64,32] per wave (rows m0..m0+15) ----
        fx4 acc1[2] = {{0,0,0,0},{0,0,0,0}};
        #pragma unroll
        for (int ks = 0; ks < 2; ++ks) {
            bfx8 a = *(const bfx8*)&sf[p][ar*64 + (((ks*4 + quad) ^ (ar & 7)) << 3)];
            #pragma unroll
            for (int j = 0; j < 2; ++j)
                acc1[j] = __builtin_amdgcn_mfma_f32_16x16x32_bf16(a, fw1[j][ks], acc1[j], 0, 0, 0);
        }
        #pragma unroll
        for (int j = 0; j < 2; ++j)
            #pragma unroll
            for (int rg = 0; rg < 4; ++rg) {
                const int row = m0 + quad*4 + rg;
                const int col = j*16 + lr;
                const float v = fmaxf(acc1[j][rg] + rb1[j], 0.f);
                sh1[row*32 + (((col >> 3) ^ (row & 3)) << 3) + (col & 7)] = (__bf16)v;
            }
        // no barrier: sh1 rows [m0, m0+16) are written and read by this wave only

        // ---- L2: [16,32]@[32,64], K=32 single step ----
        fx4 acc2[4] = {{0,0,0,0},{0,0,0,0},{0,0,0,0},{0,0,0,0}};
        {
            bfx8 a = *(const bfx8*)&sh1[ar*32 + ((quad ^ (ar & 3)) << 3)];
            #pragma unroll
            for (int j = 0; j < 4; ++j)
                acc2[j] = __builtin_amdgcn_mfma_f32_16x16x32_bf16(a, fw2[j], acc2[j], 0, 0, 0);
        }
        #pragma unroll
        for (int j = 0; j < 4; ++j)
            #pragma unroll
            for (int rg = 0; rg < 4; ++rg) {
                const int row = m0 + quad*4 + rg;
                const int col = j*16 + lr;
                const float v = fmaxf(acc2[j][rg] + rb2[j], 0.f);
                sh2[row*64 + (((col >> 3) ^ (row & 7)) << 3) + (col & 7)] = (__bf16)v;
            }

        BAR_LGKM();   // all waves' sh2 writes visible; prefetch loads stay in flight

        // ---- L3: per-wave 32-col slice over ALL 64 rows: 4 m-tiles x 2 n x 2 ks ----
        #pragma unroll
        for (int mt = 0; mt < 4; ++mt) {
            fx4 acc3[2] = {{0,0,0,0},{0,0,0,0}};
            const int arow = mt*16 + lr;
            #pragma unroll
            for (int ks = 0; ks < 2; ++ks) {
                bfx8 a = *(const bfx8*)&sh2[arow*64 + (((ks*4 + quad) ^ (arow & 7)) << 3)];
                #pragma unroll
                for (int j = 0; j < 2; ++j)
                    acc3[j] = __builtin_amdgcn_mfma_f32_16x16x32_bf16(a, fw3[j][ks], acc3[j], 0, 0, 0);
            }
            #pragma unroll
            for (int j = 0; j < 2; ++j) {
                bfx4 w;
                #pragma unroll
                for (int rg = 0; rg < 4; ++rg)
                    w[rg] = (__bf16)(acc3[j][rg] + rb3[j]);
                const int col  = wv*32 + j*16 + lr;
                const int row0 = mt*16 + quad*4;   // 4 contiguous rows
                *(bfx4*)&syT[col*64 + (((row0 >> 3) ^ (col & 7)) << 3) + (quad & 1)*4] = w;
            }
        }

        // ---- write prefetched tile into the other buffer (vmcnt waits here) ----
        if (havenext) {
            __bf16* sfn = sf[p ^ 1];
            #pragma unroll
            for (int i = 0; i < 4; ++i) {
                const int idx4 = tid + i * 256;
                const int r = idx4 >> 4;
                const int c = (idx4 & 15) * 4;
                bfx4 v;
                v[0] = (__bf16)q[i].x; v[1] = (__bf16)q[i].y;
                v[2] = (__bf16)q[i].z; v[3] = (__bf16)q[i].w;
                *(bfx4*)&sfn[r*64 + (((c >> 3) ^ (r & 7)) << 3) + (c & 7)] = v;
            }
            if (tid < RT) sseg[p ^ 1][tid] = rseg;
        }

        BAR_LGKM();   // syT + next-sf writes visible to all waves

        // ---- segment-run accumulation: 4 chunks of 8 rows, vectorized ----
        // seg_ids sorted => s[first]==s[last] implies whole chunk same segment.
        // No trailing barrier needed: next iteration's pre-L3 barrier orders
        // this scan's syT/sseg reads against their overwrite.
        #pragma unroll
        for (int ch = 0; ch < 4; ++ch) {
            const int r8 = grp*32 + ch*8;
            const bfx8 v8 = *(const bfx8*)&syT[colA*64 + (((grp*4 + ch) ^ (colA & 7)) << 3)];
            const int sA = sseg[p][r8];
            const int sB = sseg[p][r8 + 7];
            if (sA == sB) {                            // fast path (~93% of chunks)
                float sum = 0.f;
                #pragma unroll
                for (int k = 0; k < 8; ++k) sum += (float)v8[k];
                if (sA != cur_seg) {                   // uniform within group
                    if (cur_seg >= 0) {
                        atomicAdd(&sums[(size_t)cur_seg * D_OUT + colA], run_sum);
                        if (colA == 0) atomicAdd(&counts[cur_seg], (float)run_len);
                    }
                    cur_seg = sA; run_sum = sum; run_len = 8;
                } else {
                    run_sum += sum; run_len += 8;
                }
            } else {                                   // boundary chunk: per-row, from regs
                #pragma unroll
                for (int k = 0; k < 8; ++k) {
                    const int s = sseg[p][r8 + k];
                    if (s != cur_seg) {
                        if (cur_seg >= 0) {
                            atomicAdd(&sums[(size_t)cur_seg * D_OUT + colA], run_sum);
                            if (colA == 0) atomicAdd(&counts[cur_seg], (float)run_len);
                        }
                        cur_seg = s; run_sum = 0.f; run_len = 0;
                    }
                    run_sum += (float)v8[k]; run_len++;
                }
            }
        }
    }

    if (cur_seg >= 0) {
        atomicAdd(&sums[(size_t)cur_seg * D_OUT + colA], run_sum);
        if (colA == 0) atomicAdd(&counts[cur_seg], (float)run_len);
    }
}

__global__ __launch_bounds__(256) void div_kernel(
    const float* __restrict__ sums, const float* __restrict__ counts,
    float* __restrict__ out, int total)
{
    const int i = blockIdx.x * 256 + threadIdx.x;
    if (i < total) out[i] = sums[i] / fmaxf(counts[i >> 7], 1.f);
}

extern "C" void kernel_launch(void* const* d_in, const int* in_sizes, int n_in,
                              void* d_out, int out_size, void* d_ws, size_t ws_size,
                              hipStream_t stream) {
    const float* f   = (const float*)d_in[0];
    const int*   seg = (const int*)  d_in[1];
    const float* W1 = (const float*)d_in[3];
    const float* b1 = (const float*)d_in[4];
    const float* W2 = (const float*)d_in[5];
    const float* b2 = (const float*)d_in[6];
    const float* W3 = (const float*)d_in[7];
    const float* b3 = (const float*)d_in[8];
    float* out = (float*)d_out;

    const int N = in_sizes[0] / D_IN;

    float* sums   = (float*)d_ws;                 // [NSEG * D_OUT]
    float* counts = sums + (size_t)NSEG * D_OUT;  // [NSEG]

    hipMemsetAsync(d_ws, 0, ((size_t)NSEG * D_OUT + NSEG) * sizeof(float), stream);

    const int ntiles  = (N + RT - 1) / RT;
    const int nblocks = (ntiles + TPB - 1) / TPB;
    mlp_seg_mfma<<<nblocks, BLOCK, 0, stream>>>(f, seg, W1, b1, W2, b2, W3, b3,
                                                sums, counts, N, ntiles);

    const int total = NSEG * D_OUT;
    div_kernel<<<(total + 255) / 256, 256, 0, stream>>>(sums, counts, out, total);
}